// Round 6
// baseline (516.664 us; speedup 1.0000x reference)
//
#include <hip/hip_runtime.h>

#define N_TOK 16384
#define C_DIM 2048
#define E_NUM 16
#define DE_DIM 128
#define H_DIM 512

typedef __attribute__((ext_vector_type(8))) short bf16x8;
typedef __attribute__((ext_vector_type(4))) float f32x4;

__device__ __forceinline__ unsigned short f2bf(float f) {
    unsigned int u = __float_as_uint(f);
    unsigned int r = u + 0x7fffu + ((u >> 16) & 1u);   // round-to-nearest-even
    return (unsigned short)(r >> 16);
}

__device__ __forceinline__ uint4 pack8(float4 a, float4 b) {
    return make_uint4(
        (unsigned int)f2bf(a.x) | ((unsigned int)f2bf(a.y) << 16),
        (unsigned int)f2bf(a.z) | ((unsigned int)f2bf(a.w) << 16),
        (unsigned int)f2bf(b.x) | ((unsigned int)f2bf(b.y) << 16),
        (unsigned int)f2bf(b.z) | ((unsigned int)f2bf(b.w) << 16));
}

// exact-gelu via Abramowitz-Stegun 7.1.26 erf (|err| <= ~2e-7)
__device__ __forceinline__ float gelu_erf(float v) {
    float z  = v * 0.70710678118654752f;
    float az = fabsf(z);
    float t  = __builtin_amdgcn_rcpf(1.0f + 0.3275911f * az);
    float poly = t * (0.254829592f + t * (-0.284496736f + t * (1.421413741f +
                 t * (-1.453152027f + t * 1.061405429f))));
    float ex = __expf(-z * z);
    float er = copysignf(1.0f - poly * ex, z);
    return 0.5f * v * (1.0f + er);
}

// ---------------------------------------------------------------------------
// Kernel W: one-shot fp32 -> bf16 weight convert, PRE-SWIZZLED for bank-
// conflict-free LDS fragment reads after a LINEAR global_load_lds stage.
//   fcwb[e][h][ d ^ ((h&7)<<3) ] = bf16(fc_w[e][h][d])      (row = 256 B)
//   pjwb[e][d][ (h&~63) | ((h&63) ^ ((d&7)<<3)) ] = bf16(proj_w[e][d][h])
// ---------------------------------------------------------------------------
__global__ __launch_bounds__(256) void moe_conv_w(
    const float* __restrict__ fcw, const float* __restrict__ pjw,
    unsigned short* __restrict__ fcwb, unsigned short* __restrict__ pjwb)
{
    const int id = blockIdx.x * 256 + threadIdx.x;   // 0..131071
    {
        const int base = id * 8;                     // flat idx into [16][512][128]
        const int d0 = base & 127;
        const int h  = (base >> 7) & 511;
        const int dd = d0 ^ ((h & 7) << 3);
        float4 a = *reinterpret_cast<const float4*>(fcw + base);
        float4 b = *reinterpret_cast<const float4*>(fcw + base + 4);
        *reinterpret_cast<uint4*>(fcwb + (base & ~127) + dd) = pack8(a, b);
    }
    {
        const int base = id * 8;                     // flat idx into [16][128][512]
        const int h0 = base & 511;
        const int d  = (base >> 9) & 127;
        const int hh = h0 ^ ((d & 7) << 3);          // stays within 64-chunk
        float4 a = *reinterpret_cast<const float4*>(pjw + base);
        float4 b = *reinterpret_cast<const float4*>(pjw + base + 4);
        *reinterpret_cast<uint4*>(pjwb + (base & ~511) + hh) = pack8(a, b);
    }
}

// ---------------------------------------------------------------------------
// Kernel B v6: per-expert MLP with FUSED GATE.
// Evidence chain: the standalone fp64 gate was fp64-pipe-bound (537M fp64
// FMA / 223 us = 7.8 FLOP/cyc/CU = exactly 1/16 fp32 rate); standalone fp32
// variants paid scratch (r4) / ABI+divergence (r5) taxes. Here each wave
// computes its own 32 tokens x 1 expert gate logits in fp32 REGISTERS
// (gw row held in 8xfloat4, x rows loaded coalesced; 6-level butterfly),
// with a wave-uniform fp64 rescue from the SAME registers when
// |logit| < 1e-3 (margin 16x the worst-case fp32 error bound; the
// margin+rescue scheme's decisions were verified passing in round 5).
// Decisions pack into a 32-bit mask; the epilogue reads mask bits.
// The standalone gate kernel, gwf buffer, and its 134 MB HBM x-pass are
// deleted; the pre-phase also warms L1/L2 for the a1 gather.
// PRE=1: pre-swizzled bf16 weights staged via global_load_lds (L2-resident
//        per-XCD thanks to the tb-pinned bijective XCD swizzle).
// PRE=0: legacy fp32->bf16 staging fallback (needs no workspace at all).
// ---------------------------------------------------------------------------
template<int PRE>
__global__ __launch_bounds__(256, 3) void moe_expert_mlp(
    const float* __restrict__ xg,             // [N][2048] fp32
    const float* __restrict__ gw,             // [16][2048] fp32
    const float* __restrict__ gb,             // [16] fp32
    const float* __restrict__ fcw,            // [16][512][128] fp32
    const float* __restrict__ fcb,            // [16][512] fp32
    const float* __restrict__ pjw,            // [16][128][512] fp32
    const float* __restrict__ pjb,            // [16][128] fp32
    const unsigned short* __restrict__ fcwb,  // [16][512][128] bf16 swizzled
    const unsigned short* __restrict__ pjwb,  // [16][128][512] bf16 swizzled
    float* __restrict__ y)                    // [N][2048] fp32
{
    constexpr int W1S = PRE ? 128 : 136;           // shorts per W1 row
    constexpr int W2S = PRE ? 64  : 72;            // shorts per W2 row
    __shared__ unsigned short W1s[64 * W1S];
    __shared__ unsigned short W2s[128 * W2S];
    __shared__ unsigned short Hs[4 * 32 * 72];     // per-wave [tok_local][hh_local]

    const int t    = threadIdx.x;
    const int wid  = t >> 6;
    const int lane = t & 63;
    const int q    = lane >> 4;
    const int m    = lane & 15;
    // tb-pinned bijective XCD swizzle: raw = (hi:4)(e:4)(lo:3)
    //   XCD = raw&7; e is the fast slot index -> 16 e-blocks of one tb are
    //   consecutive slots on the SAME XCD -> x lines reused 16x in that L2.
    const int raw = blockIdx.x;
    const int e   = (raw >> 3) & 15;
    const int tb  = (raw & 7) | ((raw >> 7) << 3);
    const int n0  = tb * 128 + wid * 32;

    // ---- fused gate: this wave's 32 tokens, expert e (registers+shuffles) --
    float4 gwr[8];
#pragma unroll
    for (int c = 0; c < 8; ++c)
        gwr[c] = *reinterpret_cast<const float4*>(
            gw + (size_t)e * 2048 + c * 256 + lane * 4);
    const float gbe = gb[e];
    unsigned int gmask = 0;
#pragma unroll 2
    for (int tk = 0; tk < 32; ++tk) {
        const float* xr = xg + (size_t)(n0 + tk) * 2048 + lane * 4;
        float4 xv[8];
#pragma unroll
        for (int c = 0; c < 8; ++c)
            xv[c] = *reinterpret_cast<const float4*>(xr + c * 256);
        float s = 0.f;
#pragma unroll
        for (int c = 0; c < 8; ++c) {
            s = fmaf(xv[c].x, gwr[c].x, s);
            s = fmaf(xv[c].y, gwr[c].y, s);
            s = fmaf(xv[c].z, gwr[c].z, s);
            s = fmaf(xv[c].w, gwr[c].w, s);
        }
        s += __shfl_xor(s, 1);  s += __shfl_xor(s, 2);  s += __shfl_xor(s, 4);
        s += __shfl_xor(s, 8);  s += __shfl_xor(s, 16); s += __shfl_xor(s, 32);
        float l = s + gbe;      // uniform across the wave after full butterfly
        if (__builtin_expect(fabsf(l) < 1e-3f, 0)) {
            // fp64 rescue from the registers already loaded (exact products)
            double d = 0.0;
#pragma unroll
            for (int c = 0; c < 8; ++c) {
                d = fma((double)xv[c].x, (double)gwr[c].x, d);
                d = fma((double)xv[c].y, (double)gwr[c].y, d);
                d = fma((double)xv[c].z, (double)gwr[c].z, d);
                d = fma((double)xv[c].w, (double)gwr[c].w, d);
            }
            d += __shfl_xor(d, 1);  d += __shfl_xor(d, 2);  d += __shfl_xor(d, 4);
            d += __shfl_xor(d, 8);  d += __shfl_xor(d, 16); d += __shfl_xor(d, 32);
            l = (d + (double)gbe > 0.0) ? 1.f : -1.f;
        }
        gmask |= (l > 0.f ? 1u : 0u) << tk;
    }

    // A fragments for this wave's 32 tokens: A[m=lane&15][k=q*8+j]
    // gathered from x: channel of (e, d) is d*16 + e (lines warm from gate)
    bf16x8 a1[2][4];
#pragma unroll
    for (int tm = 0; tm < 2; ++tm)
#pragma unroll
        for (int kk = 0; kk < 4; ++kk) {
            const float* base = xg + (size_t)(n0 + tm * 16 + m) * 2048
                              + (kk * 32 + q * 8) * 16 + e;
            union { unsigned short u[8]; bf16x8 v; } pk;
#pragma unroll
            for (int j = 0; j < 8; ++j) pk.u[j] = f2bf(base[j * 16]);
            a1[tm][kk] = pk.v;
        }

    f32x4 oacc[2][8];
#pragma unroll
    for (int tm = 0; tm < 2; ++tm)
#pragma unroll
        for (int tn = 0; tn < 8; ++tn) oacc[tm][tn] = (f32x4){0.f, 0.f, 0.f, 0.f};

    unsigned short* HsW = &Hs[wid * 32 * 72];
    const char* W1b = reinterpret_cast<const char*>(W1s);
    const char* W2b = reinterpret_cast<const char*>(W2s);

    for (int hc = 0; hc < 8; ++hc) {
        __syncthreads();   // previous chunk's weight readers done
        if constexpr (PRE) {
            // async linear stage of pre-swizzled bf16 weights (16 KB each)
            const unsigned short* g1 = fcwb + ((size_t)e * 512 + hc * 64) * 128;
            const unsigned short* g2 = pjwb + (size_t)e * 128 * 512 + hc * 64;
#pragma unroll
            for (int it = 0; it < 4; ++it) {
                const int s = it * 2048 + t * 8;
                __builtin_amdgcn_global_load_lds(
                    (const __attribute__((address_space(1))) unsigned int*)(g1 + s),
                    (__attribute__((address_space(3))) unsigned int*)(&W1s[s]), 16, 0, 0);
            }
#pragma unroll
            for (int it = 0; it < 4; ++it) {
                const int s = it * 2048 + t * 8;
                __builtin_amdgcn_global_load_lds(
                    (const __attribute__((address_space(1))) unsigned int*)
                        (g2 + (size_t)(s >> 6) * 512 + (s & 63)),
                    (__attribute__((address_space(3))) unsigned int*)(&W2s[s]), 16, 0, 0);
            }
        } else {
            // legacy: stage fc_w chunk fp32 -> bf16, padded layout
#pragma unroll
            for (int it = 0; it < 4; ++it) {
                int idx = it * 256 + t;
                int hh = idx >> 4, ds = (idx & 15) * 8;
                const float* src = fcw + ((size_t)e * 512 + hc * 64 + hh) * 128 + ds;
                float4 va = *reinterpret_cast<const float4*>(src);
                float4 vb = *reinterpret_cast<const float4*>(src + 4);
                *reinterpret_cast<uint4*>(&W1s[hh * W1S + ds]) = pack8(va, vb);
            }
#pragma unroll
            for (int it = 0; it < 4; ++it) {
                int idx = it * 256 + t;
                int d = idx >> 3, cs = (idx & 7) * 8;
                const float* src = pjw + ((size_t)e * 128 + d) * 512 + hc * 64 + cs;
                float4 va = *reinterpret_cast<const float4*>(src);
                float4 vb = *reinterpret_cast<const float4*>(src + 4);
                *reinterpret_cast<uint4*>(&W2s[d * W2S + cs]) = pack8(va, vb);
            }
        }
        __syncthreads();

        // GEMM1: H1[32 x 64] = Xe[32 x 128] * W1[128 x 64]
        f32x4 h1[2][4];
#pragma unroll
        for (int tm = 0; tm < 2; ++tm)
#pragma unroll
            for (int tn = 0; tn < 4; ++tn) h1[tm][tn] = (f32x4){0.f, 0.f, 0.f, 0.f};
#pragma unroll
        for (int kk = 0; kk < 4; ++kk) {
#pragma unroll
            for (int tn = 0; tn < 4; ++tn) {
                bf16x8 b;
                if constexpr (PRE) {
                    const int r = tn * 16 + m;
                    b = *reinterpret_cast<const bf16x8*>(
                        W1b + r * 256 + (((kk * 32 + q * 8) * 2) ^ ((r & 7) << 4)));
                } else {
                    b = *reinterpret_cast<const bf16x8*>(
                        &W1s[(tn * 16 + m) * W1S + kk * 32 + q * 8]);
                }
                h1[0][tn] = __builtin_amdgcn_mfma_f32_16x16x32_bf16(a1[0][kk], b, h1[0][tn], 0, 0, 0);
                h1[1][tn] = __builtin_amdgcn_mfma_f32_16x16x32_bf16(a1[1][kk], b, h1[1][tn], 0, 0, 0);
            }
        }
        // bias + gelu -> Hs (C/D layout: row = tm*16+q*4+r, col = tn*16+m)
#pragma unroll
        for (int tn = 0; tn < 4; ++tn) {
            float bias = fcb[e * 512 + hc * 64 + tn * 16 + m];
#pragma unroll
            for (int tm = 0; tm < 2; ++tm)
#pragma unroll
                for (int r = 0; r < 4; ++r) {
                    float g = gelu_erf(h1[tm][tn][r] + bias);
                    HsW[(tm * 16 + q * 4 + r) * 72 + tn * 16 + m] = f2bf(g);
                }
        }
        __asm__ volatile("" ::: "memory");  // order Hs writes before A2 reads

        // GEMM2: Oacc[32 x 128] += gelu(H1)[32 x 64] * W2[64 x 128]
#pragma unroll
        for (int kk2 = 0; kk2 < 2; ++kk2) {
            bf16x8 a2_0 = *reinterpret_cast<const bf16x8*>(&HsW[(m) * 72 + kk2 * 32 + q * 8]);
            bf16x8 a2_1 = *reinterpret_cast<const bf16x8*>(&HsW[(16 + m) * 72 + kk2 * 32 + q * 8]);
#pragma unroll
            for (int tn2 = 0; tn2 < 8; ++tn2) {
                bf16x8 b2;
                if constexpr (PRE) {
                    const int r2 = tn2 * 16 + m;
                    b2 = *reinterpret_cast<const bf16x8*>(
                        W2b + r2 * 128 + (((kk2 * 32 + q * 8) * 2) ^ ((r2 & 7) << 4)));
                } else {
                    b2 = *reinterpret_cast<const bf16x8*>(
                        &W2s[(tn2 * 16 + m) * W2S + kk2 * 32 + q * 8]);
                }
                oacc[0][tn2] = __builtin_amdgcn_mfma_f32_16x16x32_bf16(a2_0, b2, oacc[0][tn2], 0, 0, 0);
                oacc[1][tn2] = __builtin_amdgcn_mfma_f32_16x16x32_bf16(a2_1, b2, oacc[1][tn2], 0, 0, 0);
            }
        }
    }

    // epilogue: (acc + proj_b) * gate_bit, store FP32 at y[n][e*128 + d]
#pragma unroll
    for (int tn2 = 0; tn2 < 8; ++tn2) {
        float pb = pjb[e * 128 + tn2 * 16 + m];
#pragma unroll
        for (int tm = 0; tm < 2; ++tm)
#pragma unroll
            for (int r = 0; r < 4; ++r) {
                const int tok = tm * 16 + q * 4 + r;
                float gv = ((gmask >> tok) & 1u) ? 1.0f : 0.0f;
                float v = (oacc[tm][tn2][r] + pb) * gv;
                y[(size_t)(n0 + tok) * 2048 + e * 128 + tn2 * 16 + m] = v;
            }
    }
}

extern "C" void kernel_launch(void* const* d_in, const int* in_sizes, int n_in,
                              void* d_out, int out_size, void* d_ws, size_t ws_size,
                              hipStream_t stream) {
    const float* x      = (const float*)d_in[0];
    const float* gate_w = (const float*)d_in[1];
    const float* gate_b = (const float*)d_in[2];
    const float* fc_w   = (const float*)d_in[3];
    const float* fc_b   = (const float*)d_in[4];
    const float* proj_w = (const float*)d_in[5];
    const float* proj_b = (const float*)d_in[6];
    float* y            = (float*)d_out;

    // ws layout: fcwb (2 MiB) | pjwb (2 MiB)
    const size_t wb_bytes  = (size_t)E_NUM * H_DIM * DE_DIM * 2;
    unsigned short* fcwb = (unsigned short*)d_ws;
    unsigned short* pjwb = (unsigned short*)((char*)d_ws + wb_bytes);
    const int use_pre = (ws_size >= 2 * wb_bytes) ? 1 : 0;

    if (use_pre) {
        moe_conv_w<<<dim3(512), dim3(256), 0, stream>>>(fc_w, proj_w, fcwb, pjwb);
        moe_expert_mlp<1><<<dim3(E_NUM * (N_TOK / 128)), dim3(256), 0, stream>>>(
            x, gate_w, gate_b, fc_w, fc_b, proj_w, proj_b, fcwb, pjwb, y);
    } else {
        moe_expert_mlp<0><<<dim3(E_NUM * (N_TOK / 128)), dim3(256), 0, stream>>>(
            x, gate_w, gate_b, fc_w, fc_b, proj_w, proj_b, fcwb, pjwb, y);
    }
}